// Round 3
// baseline (277.175 us; speedup 1.0000x reference)
//
#include <hip/hip_runtime.h>
#include <math.h>

typedef __bf16 bf16x8 __attribute__((ext_vector_type(8)));
typedef __bf16 bf16x2 __attribute__((ext_vector_type(2)));
typedef float f32x4 __attribute__((ext_vector_type(4)));
typedef float f32x16 __attribute__((ext_vector_type(16)));
typedef unsigned short u16;

#define NQ 8192
#define DMODEL 512
#define NHEAD 8
#define DH 64
#define NC 2048
#define NIDX 100000

__device__ __forceinline__ u16 f2bf(float f) {
    unsigned u = __float_as_uint(f);
    u += 0x7fffu + ((u >> 16) & 1u);
    return (u16)(u >> 16);
}
__device__ __forceinline__ float bf2f(u16 h) {
    return __uint_as_float(((unsigned)h) << 16);
}
__device__ __forceinline__ unsigned pk2(float a, float b) {
    bf16x2 t; t[0] = (__bf16)a; t[1] = (__bf16)b;   // compiler emits v_cvt_pk_bf16_f32
    return __builtin_bit_cast(unsigned, t);
}

// ---------------- elementwise f32 -> bf16 ----------------
__global__ void k_cvt_bf16(const float* __restrict__ in, u16* __restrict__ out, int n) {
    int i = (blockIdx.x * 256 + threadIdx.x) * 4;
    if (i < n) {
        float4 v = *(const float4*)(in + i);
        ushort4 o;
        o.x = f2bf(v.x); o.y = f2bf(v.y); o.z = f2bf(v.z); o.w = f2bf(v.w);
        *(ushort4*)(out + i) = o;
    }
}

// ---------------- transpose (f32 or bf16 in) -> bf16 out[c][r] = in[r][c] ----------------
template <int IN_F32>
__global__ void k_transpose_bf16(const void* __restrict__ in_, u16* __restrict__ out, int R, int C) {
    __shared__ float tile[32][33];
    int c0 = blockIdx.x * 32, r0 = blockIdx.y * 32;
    int tx = threadIdx.x, ty = threadIdx.y;  // (32,8)
#pragma unroll
    for (int i = 0; i < 4; i++) {
        int r = r0 + ty + i * 8;
        float v;
        if (IN_F32) v = ((const float*)in_)[(size_t)r * C + c0 + tx];
        else        v = bf2f(((const u16*)in_)[(size_t)r * C + c0 + tx]);
        tile[ty + i * 8][tx] = v;
    }
    __syncthreads();
#pragma unroll
    for (int i = 0; i < 4; i++) {
        out[(size_t)(c0 + ty + i * 8) * R + r0 + tx] = f2bf(tile[tx][ty + i * 8]);
    }
}

// ---------------- histogram + log2 bias ----------------
__global__ void k_hist(const int* __restrict__ idx, int* __restrict__ counts, int n) {
    for (int i = blockIdx.x * blockDim.x + threadIdx.x; i < n; i += gridDim.x * blockDim.x)
        atomicAdd(&counts[idx[i]], 1);
}
__global__ void k_logbias(const int* __restrict__ counts, float* __restrict__ bias, int n) {
    int i = blockIdx.x * blockDim.x + threadIdx.x;
    if (i < n) bias[i] = log2f((float)counts[i]);   // log2 domain; log2(0)=-inf masks empty
}

// ---------------- bcomb = b_proj @ W_q + b_q  (f32) ----------------
__global__ void k_bcomb(const float* __restrict__ bp, const float* __restrict__ Wq,
                        const float* __restrict__ bq, float* __restrict__ bc) {
    int j = blockIdx.x * 256 + threadIdx.x;
    float s = bq[j];
    for (int k = 0; k < DMODEL; k++) s += bp[k] * Wq[(size_t)k * DMODEL + j];
    bc[j] = s;
}

// ---------------- bf16 GEMM: C[M][N] = A[M][K] * Bt[N][K]^T + bias[N] ----------------
__global__ __launch_bounds__(256) void k_gemm_bt(
    const u16* __restrict__ A, const u16* __restrict__ Bt,
    const float* __restrict__ bias, u16* __restrict__ Cmat,
    int M, int N, int K)
{
    constexpr int LDP = 40;
    __shared__ __align__(16) u16 As[128 * LDP];
    __shared__ __align__(16) u16 Bs[128 * LDP];
    int tid = threadIdx.x;
    int lane = tid & 63, wid = tid >> 6;
    int wrow = (wid >> 1) * 64, wcol = (wid & 1) * 64;
    int m0 = blockIdx.y * 128, n0 = blockIdx.x * 128;
    int lr = lane & 15, lg = lane >> 4;
    f32x4 acc[4][4] = {};

    for (int k0 = 0; k0 < K; k0 += 32) {
#pragma unroll
        for (int c = 0; c < 2; c++) {
            int ch = tid + c * 256;
            int row = ch >> 2, colc = (ch & 3) * 8;
            uint4 av = *(const uint4*)(A + (size_t)(m0 + row) * K + k0 + colc);
            *(uint4*)(&As[row * LDP + colc]) = av;
            uint4 bv = *(const uint4*)(Bt + (size_t)(n0 + row) * K + k0 + colc);
            *(uint4*)(&Bs[row * LDP + colc]) = bv;
        }
        __syncthreads();
        bf16x8 af[4], bfr[4];
#pragma unroll
        for (int m = 0; m < 4; m++)
            af[m] = *(const bf16x8*)(&As[(wrow + m * 16 + lr) * LDP + lg * 8]);
#pragma unroll
        for (int n = 0; n < 4; n++)
            bfr[n] = *(const bf16x8*)(&Bs[(wcol + n * 16 + lr) * LDP + lg * 8]);
#pragma unroll
        for (int m = 0; m < 4; m++)
#pragma unroll
            for (int n = 0; n < 4; n++)
                acc[m][n] = __builtin_amdgcn_mfma_f32_16x16x32_bf16(af[m], bfr[n], acc[m][n], 0, 0, 0);
        __syncthreads();
    }
#pragma unroll
    for (int n = 0; n < 4; n++) {
        int col = n0 + wcol + n * 16 + lr;
        float bv = bias[col];
#pragma unroll
        for (int m = 0; m < 4; m++) {
            int rbase = m0 + wrow + m * 16 + lg * 4;
#pragma unroll
            for (int r = 0; r < 4; r++)
                Cmat[(size_t)(rbase + r) * N + col] = f2bf(acc[m][n][r] + bv);
        }
    }
}

// ---------------- fused attention + LayerNorm ----------------
// grid(NQ/32); block 1024 = 16 waves = 8 heads x 2 c-halves. Wave: 32 q-rows,
// one head, 1024 centroids. Swapped QK^T (mfma(K,Q)) -> lane-local softmax,
// in-register P repack (pk2 + shfl_xor(32)) -> PV as O^T. Barrier-free main loop.
__global__ __launch_bounds__(1024, 4) void k_attn2(
    const u16* __restrict__ Q, const u16* __restrict__ Km, const u16* __restrict__ Vt,
    const float* __restrict__ bias2, const float* __restrict__ ln_g,
    const float* __restrict__ ln_b, float* __restrict__ Out, float scale2)
{
    __shared__ float sbias[NC];                    // 8 KB (log2 domain)
    __shared__ unsigned sOp[8 * 32 * 32];          // 32 KB: half1 partial O; reused as sO[32][256]
    __shared__ float sm[256], sl[256];             // per (h,q) running max / sum

    int tid = threadIdx.x;
    int lane = tid & 63, wid = tid >> 6;
    int h = wid & 7, hf = wid >> 3;
    int ql = lane & 31, hi = lane >> 5;
    int q0 = blockIdx.x * 32;
    int hbase = h * DH;

    sbias[tid] = bias2[tid];
    sbias[tid + 1024] = bias2[tid + 1024];
    __syncthreads();

    // Q B-frags (persist): Q[q0+ql][hbase + m*16 + hi*8 ..+8]
    bf16x8 qf[4];
#pragma unroll
    for (int m = 0; m < 4; m++)
        qf[m] = *(const bf16x8*)(Q + (size_t)(q0 + ql) * DMODEL + hbase + m * 16 + hi * 8);

    int cbase = hf * (NC / 2);

    // preload chunk 0 K/V frags
    bf16x8 kf[4], vf[4];
#pragma unroll
    for (int m = 0; m < 4; m++)
        kf[m] = *(const bf16x8*)(Km + (size_t)(cbase + ql) * DMODEL + hbase + m * 16 + hi * 8);
#pragma unroll
    for (int T = 0; T < 2; T++)
#pragma unroll
        for (int s = 0; s < 2; s++)
            vf[T * 2 + s] = *(const bf16x8*)(Vt + (size_t)(hbase + T * 32 + ql) * NC + cbase + s * 16 + hi * 8);

    f32x16 o0 = {}, o1 = {};
    float m_run = -1e30f, l_part = 0.f;

    for (int t = 0; t < NC / 64; t++) {
        int c0 = cbase + t * 32;
        int cn = cbase + ((t + 1) & (NC / 64 - 1)) * 32;   // wrapped (last prefetch unused)

        // bias quads: c = c0 + 8j + 4hi + {0..3}
        f32x4 bq[4];
#pragma unroll
        for (int j = 0; j < 4; j++)
            bq[j] = *(const f32x4*)(sbias + c0 + 8 * j + 4 * hi);

        // QK^T (swapped): acc[c][q]
        f32x16 acc = {};
        __builtin_amdgcn_s_setprio(1);
#pragma unroll
        for (int m = 0; m < 4; m++)
            acc = __builtin_amdgcn_mfma_f32_32x32x16_bf16(kf[m], qf[m], acc, 0, 0, 0);
        __builtin_amdgcn_s_setprio(0);

        // prefetch next K into just-freed regs
#pragma unroll
        for (int m = 0; m < 4; m++)
            kf[m] = *(const bf16x8*)(Km + (size_t)(cn + ql) * DMODEL + hbase + m * 16 + hi * 8);

        float s[16];
#pragma unroll
        for (int r = 0; r < 16; r++)
            s[r] = acc[r] * scale2 + bq[r >> 2][r & 3];

        float mx = s[0];
#pragma unroll
        for (int r = 1; r < 16; r++) mx = fmaxf(mx, s[r]);
        mx = fmaxf(mx, __shfl_xor(mx, 32));

        if (__any(mx > m_run + 11.f)) {            // defer-max (log2 domain, ~e^7.6)
            float mn = fmaxf(m_run, mx);
            float corr = exp2f(m_run - mn);
            m_run = mn; l_part *= corr;
#pragma unroll
            for (int r = 0; r < 16; r++) { o0[r] *= corr; o1[r] *= corr; }
        }

        float rs = 0.f;
#pragma unroll
        for (int r = 0; r < 16; r++) {
            s[r] = exp2f(s[r] - m_run);
            rs += s[r];
        }
        l_part += rs;

        // pack P pairs and exchange with partner lane (lane^32)
        unsigned u[8], pu[8];
#pragma unroll
        for (int j = 0; j < 8; j++) u[j] = pk2(s[2 * j], s[2 * j + 1]);
#pragma unroll
        for (int j = 0; j < 8; j++) pu[j] = (unsigned)__shfl_xor((int)u[j], 32);

        uint4 w0, w1;
        w0.x = hi ? pu[2] : u[0];  w0.y = hi ? pu[3] : u[1];
        w0.z = hi ? u[2] : pu[0];  w0.w = hi ? u[3] : pu[1];
        w1.x = hi ? pu[6] : u[4];  w1.y = hi ? pu[7] : u[5];
        w1.z = hi ? u[6] : pu[4];  w1.w = hi ? u[7] : pu[5];
        bf16x8 pb0 = __builtin_bit_cast(bf16x8, w0);
        bf16x8 pb1 = __builtin_bit_cast(bf16x8, w1);

        // PV: O^T[d][q] += V^T-frag x P-frag
        __builtin_amdgcn_s_setprio(1);
        o0 = __builtin_amdgcn_mfma_f32_32x32x16_bf16(vf[0], pb0, o0, 0, 0, 0);
        o0 = __builtin_amdgcn_mfma_f32_32x32x16_bf16(vf[1], pb1, o0, 0, 0, 0);
        o1 = __builtin_amdgcn_mfma_f32_32x32x16_bf16(vf[2], pb0, o1, 0, 0, 0);
        o1 = __builtin_amdgcn_mfma_f32_32x32x16_bf16(vf[3], pb1, o1, 0, 0, 0);
        __builtin_amdgcn_s_setprio(0);

        // prefetch next V into just-freed regs
#pragma unroll
        for (int T = 0; T < 2; T++)
#pragma unroll
            for (int ss = 0; ss < 2; ss++)
                vf[T * 2 + ss] = *(const bf16x8*)(Vt + (size_t)(hbase + T * 32 + ql) * NC + cn + ss * 16 + hi * 8);
    }

    float l_tot = l_part + __shfl_xor(l_part, 32);

    // ---- merge halves + LN (once per kernel; LDS conflicts here are negligible)
    if (hf == 1) {
#pragma unroll
        for (int T = 0; T < 2; T++)
#pragma unroll
            for (int j = 0; j < 8; j++) {
                int dw = T * 16 + (j & 1) + 4 * (j >> 1) + 2 * hi;
                float a = (T == 0) ? o0[2 * j] : o1[2 * j];
                float b = (T == 0) ? o0[2 * j + 1] : o1[2 * j + 1];
                sOp[(h * 32 + ql) * 32 + dw] = pk2(a, b);
            }
        if (hi == 0) { sm[h * 32 + ql] = m_run; sl[h * 32 + ql] = l_tot; }
    }
    __syncthreads();

    float mrg[32];
    if (hf == 0) {
        float pm = sm[h * 32 + ql], pl = sl[h * 32 + ql];
        float mN = fmaxf(m_run, pm);
        float w0_ = exp2f(m_run - mN), w1_ = exp2f(pm - mN);
        float inv = 1.0f / (l_tot * w0_ + pl * w1_);
#pragma unroll
        for (int T = 0; T < 2; T++)
#pragma unroll
            for (int j = 0; j < 8; j++) {
                int dw = T * 16 + (j & 1) + 4 * (j >> 1) + 2 * hi;
                unsigned pv = sOp[(h * 32 + ql) * 32 + dw];
                float a = (T == 0) ? o0[2 * j] : o1[2 * j];
                float b = (T == 0) ? o0[2 * j + 1] : o1[2 * j + 1];
                mrg[T * 16 + 2 * j]     = (a * w0_ + bf2f((u16)(pv & 0xffff)) * w1_) * inv;
                mrg[T * 16 + 2 * j + 1] = (b * w0_ + bf2f((u16)(pv >> 16)) * w1_) * inv;
            }
    }
    __syncthreads();
    if (hf == 0) {
#pragma unroll
        for (int T = 0; T < 2; T++)
#pragma unroll
            for (int j = 0; j < 8; j++) {
                int dw = T * 16 + (j & 1) + 4 * (j >> 1) + 2 * hi;
                sOp[ql * 256 + h * 32 + dw] = pk2(mrg[T * 16 + 2 * j], mrg[T * 16 + 2 * j + 1]);
            }
    }
    __syncthreads();

    // LayerNorm: wave wid handles rows 2*wid, 2*wid+1
#pragma unroll
    for (int rr = 0; rr < 2; rr++) {
        int r = wid * 2 + rr;
        uint4 pw = *(const uint4*)(&sOp[r * 256 + lane * 4]);
        float v[8];
        v[0] = bf2f((u16)(pw.x & 0xffff)); v[1] = bf2f((u16)(pw.x >> 16));
        v[2] = bf2f((u16)(pw.y & 0xffff)); v[3] = bf2f((u16)(pw.y >> 16));
        v[4] = bf2f((u16)(pw.z & 0xffff)); v[5] = bf2f((u16)(pw.z >> 16));
        v[6] = bf2f((u16)(pw.w & 0xffff)); v[7] = bf2f((u16)(pw.w >> 16));
        float sum = 0.f, sq = 0.f;
#pragma unroll
        for (int j = 0; j < 8; j++) { sum += v[j]; sq += v[j] * v[j]; }
#pragma unroll
        for (int msk = 1; msk <= 32; msk <<= 1) { sum += __shfl_xor(sum, msk); sq += __shfl_xor(sq, msk); }
        float mu = sum * (1.f / DMODEL);
        float var = sq * (1.f / DMODEL) - mu * mu;
        float rstd = rsqrtf(var + 1e-5f);
        float4 g0 = *(const float4*)(ln_g + lane * 8);
        float4 g1 = *(const float4*)(ln_g + lane * 8 + 4);
        float4 b0 = *(const float4*)(ln_b + lane * 8);
        float4 b1 = *(const float4*)(ln_b + lane * 8 + 4);
        float o[8];
        o[0] = (v[0] - mu) * rstd * g0.x + b0.x; o[1] = (v[1] - mu) * rstd * g0.y + b0.y;
        o[2] = (v[2] - mu) * rstd * g0.z + b0.z; o[3] = (v[3] - mu) * rstd * g0.w + b0.w;
        o[4] = (v[4] - mu) * rstd * g1.x + b1.x; o[5] = (v[5] - mu) * rstd * g1.y + b1.y;
        o[6] = (v[6] - mu) * rstd * g1.z + b1.z; o[7] = (v[7] - mu) * rstd * g1.w + b1.w;
        float* op = Out + (size_t)(q0 + r) * DMODEL + lane * 8;
        *(float4*)op = *(float4*)&o[0];
        *(float4*)(op + 4) = *(float4*)&o[4];
    }
}

extern "C" void kernel_launch(void* const* d_in, const int* in_sizes, int n_in,
                              void* d_out, int out_size, void* d_ws, size_t ws_size,
                              hipStream_t stream)
{
    const float* x      = (const float*)d_in[0];
    const float* W_proj = (const float*)d_in[1];
    const float* b_proj = (const float*)d_in[2];
    const float* W_q    = (const float*)d_in[3];
    const float* b_q    = (const float*)d_in[4];
    const float* W_k    = (const float*)d_in[5];
    const float* b_k    = (const float*)d_in[6];
    const float* W_v    = (const float*)d_in[7];
    const float* b_v    = (const float*)d_in[8];
    const float* k_buf  = (const float*)d_in[9];
    const float* v_buf  = (const float*)d_in[10];
    const float* ln_g   = (const float*)d_in[11];
    const float* ln_b   = (const float*)d_in[12];
    const int*   c_idx  = (const int*)d_in[13];
    float* out = (float*)d_out;

    char* ws = (char*)d_ws;
    size_t off = 0;
    auto alloc = [&](size_t bytes) -> void* {
        void* p = ws + off;
        off += (bytes + 255) & ~(size_t)255;
        return p;
    };
    u16* x_bf   = (u16*)alloc((size_t)NQ * DMODEL * 2);
    u16* kb_bf  = (u16*)alloc((size_t)NC * DMODEL * 2);
    u16* vb_bf  = (u16*)alloc((size_t)NC * DMODEL * 2);
    u16* Wp_bf  = (u16*)alloc((size_t)DMODEL * DMODEL * 2);
    u16* Wq_t   = (u16*)alloc((size_t)DMODEL * DMODEL * 2);
    u16* Wk_t   = (u16*)alloc((size_t)DMODEL * DMODEL * 2);
    u16* Wv_t   = (u16*)alloc((size_t)DMODEL * DMODEL * 2);
    u16* WcombT = (u16*)alloc((size_t)DMODEL * DMODEL * 2);
    u16* Qm     = (u16*)alloc((size_t)NQ * DMODEL * 2);
    u16* Km     = (u16*)alloc((size_t)NC * DMODEL * 2);
    u16* Vm     = (u16*)alloc((size_t)NC * DMODEL * 2);
    u16* Vtm    = (u16*)alloc((size_t)DMODEL * NC * 2);
    int*   counts = (int*)alloc(NC * 4);
    float* bias2  = (float*)alloc(NC * 4);
    float* bcomb  = (float*)alloc(DMODEL * 4);
    float* zb     = (float*)alloc(DMODEL * 4);

    hipMemsetAsync(counts, 0, NC * 4, stream);
    hipMemsetAsync(zb, 0, DMODEL * 4, stream);

    k_cvt_bf16<<<dim3((NQ * DMODEL / 4 + 255) / 256), dim3(256), 0, stream>>>(x, x_bf, NQ * DMODEL);
    k_cvt_bf16<<<dim3((NC * DMODEL / 4 + 255) / 256), dim3(256), 0, stream>>>(k_buf, kb_bf, NC * DMODEL);
    k_cvt_bf16<<<dim3((NC * DMODEL / 4 + 255) / 256), dim3(256), 0, stream>>>(v_buf, vb_bf, NC * DMODEL);
    k_cvt_bf16<<<dim3((DMODEL * DMODEL / 4 + 255) / 256), dim3(256), 0, stream>>>(W_proj, Wp_bf, DMODEL * DMODEL);
    k_transpose_bf16<1><<<dim3(16, 16), dim3(32, 8), 0, stream>>>(W_q, Wq_t, DMODEL, DMODEL);
    k_transpose_bf16<1><<<dim3(16, 16), dim3(32, 8), 0, stream>>>(W_k, Wk_t, DMODEL, DMODEL);
    k_transpose_bf16<1><<<dim3(16, 16), dim3(32, 8), 0, stream>>>(W_v, Wv_t, DMODEL, DMODEL);
    k_hist<<<dim3(128), dim3(256), 0, stream>>>(c_idx, counts, NIDX);
    k_logbias<<<dim3(8), dim3(256), 0, stream>>>(counts, bias2, NC);
    k_bcomb<<<dim3(2), dim3(256), 0, stream>>>(b_proj, W_q, b_q, bcomb);

    // WcombT = Wq^T @ Wp^T  (so Q = x @ Wcomb uses Bt=WcombT)
    k_gemm_bt<<<dim3(4, 4), dim3(256), 0, stream>>>(Wq_t, Wp_bf, zb, WcombT, DMODEL, DMODEL, DMODEL);
    k_gemm_bt<<<dim3(4, 64), dim3(256), 0, stream>>>(x_bf, WcombT, bcomb, Qm, NQ, DMODEL, DMODEL);
    k_gemm_bt<<<dim3(4, 16), dim3(256), 0, stream>>>(kb_bf, Wk_t, b_k, Km, NC, DMODEL, DMODEL);
    k_gemm_bt<<<dim3(4, 16), dim3(256), 0, stream>>>(vb_bf, Wv_t, b_v, Vm, NC, DMODEL, DMODEL);
    k_transpose_bf16<0><<<dim3(16, 64), dim3(32, 8), 0, stream>>>(Vm, Vtm, NC, DMODEL);

    // scale2 = (1/sqrt(512)) * log2(e); bias2 already log2-domain
    k_attn2<<<dim3(NQ / 32), dim3(1024), 0, stream>>>(Qm, Km, Vtm, bias2, ln_g, ln_b, out, 0.06375872f);
    (void)in_sizes; (void)n_in; (void)out_size; (void)ws_size;
}

// Round 4
// 239.156 us; speedup vs baseline: 1.1590x; 1.1590x over previous
//
#include <hip/hip_runtime.h>
#include <math.h>

typedef __bf16 bf16x8 __attribute__((ext_vector_type(8)));
typedef __bf16 bf16x2 __attribute__((ext_vector_type(2)));
typedef float f32x4 __attribute__((ext_vector_type(4)));
typedef float f32x16 __attribute__((ext_vector_type(16)));
typedef unsigned short u16;

#define NQ 8192
#define DMODEL 512
#define NHEAD 8
#define DH 64
#define NC 2048
#define NIDX 100000

__device__ __forceinline__ u16 f2bf(float f) {
    unsigned u = __float_as_uint(f);
    u += 0x7fffu + ((u >> 16) & 1u);
    return (u16)(u >> 16);
}
__device__ __forceinline__ float bf2f(u16 h) {
    return __uint_as_float(((unsigned)h) << 16);
}
__device__ __forceinline__ unsigned pk2(float a, float b) {
    bf16x2 t; t[0] = (__bf16)a; t[1] = (__bf16)b;   // v_cvt_pk_bf16_f32
    return __builtin_bit_cast(unsigned, t);
}
// swizzled u32 index into sO[32][256]: 16B-block XOR by row
__device__ __forceinline__ int soff(int q, int col) {
    return q * 256 + ((((col >> 2) ^ (q & 7)) << 2) | (col & 3));
}

// ---------------- fused preamble: converts + transposes + hist + bcomb ----------------
// grid segments (256 thr each):
//  [0,4096)      x f32->bf16          [4096,5120) k_buf    [5120,6144) v_buf
//  [6144,6400)   W_proj f32->bf16
//  [6400,6656)   W_q^T  [6656,6912) W_k^T  [6912,7168) W_v^T   (bf16 out)
//  [7168,7296)   histogram of c_idx
//  [7296,7298)   bcomb = b_proj @ W_q + b_q
__global__ __launch_bounds__(256) void k_prep(
    const float* __restrict__ x, const float* __restrict__ kb, const float* __restrict__ vb,
    const float* __restrict__ Wp, const float* __restrict__ Wq, const float* __restrict__ Wk,
    const float* __restrict__ Wv, const float* __restrict__ bp, const float* __restrict__ bq_,
    const int* __restrict__ cidx,
    u16* __restrict__ x_bf, u16* __restrict__ kb_bf, u16* __restrict__ vb_bf,
    u16* __restrict__ Wp_bf, u16* __restrict__ Wq_t, u16* __restrict__ Wk_t,
    u16* __restrict__ Wv_t, int* __restrict__ counts, float* __restrict__ bcomb)
{
    __shared__ float tile[32][33];
    int bid = blockIdx.x, tid = threadIdx.x;
    if (bid < 6400) {
        const float* src; u16* dst; int i;
        if (bid < 4096)      { src = x;  dst = x_bf;  i = bid; }
        else if (bid < 5120) { src = kb; dst = kb_bf; i = bid - 4096; }
        else if (bid < 6144) { src = vb; dst = vb_bf; i = bid - 5120; }
        else                 { src = Wp; dst = Wp_bf; i = bid - 6144; }
        int e = (i * 256 + tid) * 4;
        float4 v = *(const float4*)(src + e);
        ushort4 o;
        o.x = f2bf(v.x); o.y = f2bf(v.y); o.z = f2bf(v.z); o.w = f2bf(v.w);
        *(ushort4*)(dst + e) = o;
    } else if (bid < 7168) {
        const float* W; u16* Wt; int tb;
        if (bid < 6656)      { W = Wq; Wt = Wq_t; tb = bid - 6400; }
        else if (bid < 6912) { W = Wk; Wt = Wk_t; tb = bid - 6656; }
        else                 { W = Wv; Wt = Wv_t; tb = bid - 6912; }
        int c0 = (tb & 15) * 32, r0 = (tb >> 4) * 32;
        int tx = tid & 31, ty = tid >> 5;
#pragma unroll
        for (int i = 0; i < 4; i++)
            tile[ty + i * 8][tx] = W[(size_t)(r0 + ty + i * 8) * DMODEL + c0 + tx];
        __syncthreads();
#pragma unroll
        for (int i = 0; i < 4; i++)
            Wt[(size_t)(c0 + ty + i * 8) * DMODEL + r0 + tx] = f2bf(tile[tx][ty + i * 8]);
    } else if (bid < 7296) {
        for (int i = (bid - 7168) * 256 + tid; i < NIDX; i += 128 * 256)
            atomicAdd(&counts[cidx[i]], 1);
    } else {
        int j = (bid - 7296) * 256 + tid;
        float s = bq_[j];
        for (int k = 0; k < DMODEL; k++) s += bp[k] * Wq[(size_t)k * DMODEL + j];
        bcomb[j] = s;
    }
}

// ---------------- bf16 GEMM: C = A[M][K] * Bt[N][K]^T + bias[N] ----------------
// OUT_T=0: Cmat[M][N] row-major. OUT_T=1: Cmat is [N][M] (transposed output).
template <int OUT_T>
__global__ __launch_bounds__(256) void k_gemm_bt(
    const u16* __restrict__ A, const u16* __restrict__ Bt,
    const float* __restrict__ bias, u16* __restrict__ Cmat,
    int M, int N, int K)
{
    constexpr int LDP = 40;
    __shared__ __align__(16) u16 As[128 * LDP];
    __shared__ __align__(16) u16 Bs[128 * LDP];
    int tid = threadIdx.x;
    int lane = tid & 63, wid = tid >> 6;
    int wrow = (wid >> 1) * 64, wcol = (wid & 1) * 64;
    int m0 = blockIdx.y * 128, n0 = blockIdx.x * 128;
    int lr = lane & 15, lg = lane >> 4;
    f32x4 acc[4][4] = {};

    for (int k0 = 0; k0 < K; k0 += 32) {
#pragma unroll
        for (int c = 0; c < 2; c++) {
            int ch = tid + c * 256;
            int row = ch >> 2, colc = (ch & 3) * 8;
            uint4 av = *(const uint4*)(A + (size_t)(m0 + row) * K + k0 + colc);
            *(uint4*)(&As[row * LDP + colc]) = av;
            uint4 bv = *(const uint4*)(Bt + (size_t)(n0 + row) * K + k0 + colc);
            *(uint4*)(&Bs[row * LDP + colc]) = bv;
        }
        __syncthreads();
        bf16x8 af[4], bfr[4];
#pragma unroll
        for (int m = 0; m < 4; m++)
            af[m] = *(const bf16x8*)(&As[(wrow + m * 16 + lr) * LDP + lg * 8]);
#pragma unroll
        for (int n = 0; n < 4; n++)
            bfr[n] = *(const bf16x8*)(&Bs[(wcol + n * 16 + lr) * LDP + lg * 8]);
#pragma unroll
        for (int m = 0; m < 4; m++)
#pragma unroll
            for (int n = 0; n < 4; n++)
                acc[m][n] = __builtin_amdgcn_mfma_f32_16x16x32_bf16(af[m], bfr[n], acc[m][n], 0, 0, 0);
        __syncthreads();
    }
#pragma unroll
    for (int n = 0; n < 4; n++) {
        int col = n0 + wcol + n * 16 + lr;
        float bv = bias ? bias[col] : 0.0f;
#pragma unroll
        for (int m = 0; m < 4; m++) {
            int rbase = m0 + wrow + m * 16 + lg * 4;
            if (OUT_T) {
                ushort4 o4;
                o4.x = f2bf(acc[m][n][0] + bv);
                o4.y = f2bf(acc[m][n][1] + bv);
                o4.z = f2bf(acc[m][n][2] + bv);
                o4.w = f2bf(acc[m][n][3] + bv);
                *(ushort4*)(Cmat + (size_t)col * M + rbase) = o4;
            } else {
#pragma unroll
                for (int r = 0; r < 4; r++)
                    Cmat[(size_t)(rbase + r) * N + col] = f2bf(acc[m][n][r] + bv);
            }
        }
    }
}

// ---------------- fused attention + LayerNorm ----------------
// grid(NQ/32); block 1024 = 16 waves = 8 heads x 2 c-halves. Wave: 32 q, one head,
// 1024 centroids. Swapped QK^T (mfma(K,Q)) -> lane-local softmax, in-register P
// repack (pk2 + shfl_xor(32)) -> PV as O^T. V loaded mid-iteration (short live
// range; peak VGPR ~112 < 128 cap). log2-bias computed in-kernel from counts.
__global__ __launch_bounds__(1024, 4) void k_attn3(
    const u16* __restrict__ Q, const u16* __restrict__ Km, const u16* __restrict__ Vt,
    const int* __restrict__ counts, const float* __restrict__ ln_g,
    const float* __restrict__ ln_b, float* __restrict__ Out, float scale2)
{
    __shared__ float sbias[NC];          // 8 KB, log2(count)
    __shared__ unsigned sO[32 * 256];    // 32 KB, swizzled packed O
    __shared__ float sm[256], sl[256];

    int tid = threadIdx.x;
    int lane = tid & 63, wid = tid >> 6;
    int h = wid & 7, hf = wid >> 3;
    int ql = lane & 31, hi = lane >> 5;
    int q0 = blockIdx.x * 32;
    int hbase = h * DH;

    sbias[tid] = log2f((float)counts[tid]);
    sbias[tid + 1024] = log2f((float)counts[tid + 1024]);

    bf16x8 qf[4];
#pragma unroll
    for (int m = 0; m < 4; m++)
        qf[m] = *(const bf16x8*)(Q + (size_t)(q0 + ql) * DMODEL + hbase + m * 16 + hi * 8);

    int cbase = hf * (NC / 2);
    bf16x8 kf[4];
#pragma unroll
    for (int m = 0; m < 4; m++)
        kf[m] = *(const bf16x8*)(Km + (size_t)(cbase + ql) * DMODEL + hbase + m * 16 + hi * 8);

    f32x16 o0 = {}, o1 = {};
    float m_run = -1e30f, l_part = 0.f;

    __syncthreads();   // sbias ready

    for (int t = 0; t < NC / 64; t++) {
        int c0 = cbase + t * 32;
        int cn = cbase + ((t + 1) & (NC / 64 - 1)) * 32;

        f32x4 bq[4];
#pragma unroll
        for (int j = 0; j < 4; j++)
            bq[j] = *(const f32x4*)(sbias + c0 + 8 * j + 4 * hi);

        // QK^T (swapped): acc[c][q]
        f32x16 acc = {};
        __builtin_amdgcn_s_setprio(1);
#pragma unroll
        for (int m = 0; m < 4; m++)
            acc = __builtin_amdgcn_mfma_f32_32x32x16_bf16(kf[m], qf[m], acc, 0, 0, 0);
        __builtin_amdgcn_s_setprio(0);

        // prefetch next K into just-freed regs (consumed next iteration)
#pragma unroll
        for (int m = 0; m < 4; m++)
            kf[m] = *(const bf16x8*)(Km + (size_t)(cn + ql) * DMODEL + hbase + m * 16 + hi * 8);

        // V for CURRENT chunk: short live range, latency covered by softmax
        bf16x8 vf[4];
#pragma unroll
        for (int T = 0; T < 2; T++)
#pragma unroll
            for (int ss = 0; ss < 2; ss++)
                vf[T * 2 + ss] = *(const bf16x8*)(Vt + (size_t)(hbase + T * 32 + ql) * NC + c0 + ss * 16 + hi * 8);

        float s[16];
#pragma unroll
        for (int r = 0; r < 16; r++)
            s[r] = acc[r] * scale2 + bq[r >> 2][r & 3];

        float mx = s[0];
#pragma unroll
        for (int r = 1; r < 16; r++) mx = fmaxf(mx, s[r]);
        mx = fmaxf(mx, __shfl_xor(mx, 32));

        if (__any(mx > m_run + 11.f)) {            // defer-max (log2 domain)
            float mn = fmaxf(m_run, mx);
            float corr = exp2f(m_run - mn);
            m_run = mn; l_part *= corr;
#pragma unroll
            for (int r = 0; r < 16; r++) { o0[r] *= corr; o1[r] *= corr; }
        }

        float rs = 0.f;
#pragma unroll
        for (int r = 0; r < 16; r++) {
            s[r] = exp2f(s[r] - m_run);
            rs += s[r];
        }
        l_part += rs;

        // pack P pairs, exchange with partner lane (lane^32), assemble B-frags
        unsigned u[8], pu[8];
#pragma unroll
        for (int j = 0; j < 8; j++) u[j] = pk2(s[2 * j], s[2 * j + 1]);
#pragma unroll
        for (int j = 0; j < 8; j++) pu[j] = (unsigned)__shfl_xor((int)u[j], 32);

        uint4 w0, w1;
        w0.x = hi ? pu[2] : u[0];  w0.y = hi ? pu[3] : u[1];
        w0.z = hi ? u[2] : pu[0];  w0.w = hi ? u[3] : pu[1];
        w1.x = hi ? pu[6] : u[4];  w1.y = hi ? pu[7] : u[5];
        w1.z = hi ? u[6] : pu[4];  w1.w = hi ? u[7] : pu[5];
        bf16x8 pb0 = __builtin_bit_cast(bf16x8, w0);
        bf16x8 pb1 = __builtin_bit_cast(bf16x8, w1);

        // PV: O^T[d][q] += V^T-frag x P-frag
        __builtin_amdgcn_s_setprio(1);
        o0 = __builtin_amdgcn_mfma_f32_32x32x16_bf16(vf[0], pb0, o0, 0, 0, 0);
        o0 = __builtin_amdgcn_mfma_f32_32x32x16_bf16(vf[1], pb1, o0, 0, 0, 0);
        o1 = __builtin_amdgcn_mfma_f32_32x32x16_bf16(vf[2], pb0, o1, 0, 0, 0);
        o1 = __builtin_amdgcn_mfma_f32_32x32x16_bf16(vf[3], pb1, o1, 0, 0, 0);
        __builtin_amdgcn_s_setprio(0);
    }

    float l_tot = l_part + __shfl_xor(l_part, 32);

    // ---- phase 1: upper half writes unnormalized partials (swizzled)
    if (hf == 1) {
#pragma unroll
        for (int T = 0; T < 2; T++)
#pragma unroll
            for (int j = 0; j < 8; j++) {
                int dw = T * 16 + (j & 1) + 4 * (j >> 1) + 2 * hi;
                float a = (T == 0) ? o0[2 * j] : o1[2 * j];
                float b = (T == 0) ? o0[2 * j + 1] : o1[2 * j + 1];
                sO[soff(ql, h * 32 + dw)] = pk2(a, b);
            }
        if (hi == 0) { sm[h * 32 + ql] = m_run; sl[h * 32 + ql] = l_tot; }
    }
    __syncthreads();

    // ---- phase 2: lower half merges + normalizes in place
    if (hf == 0) {
        float pm = sm[h * 32 + ql], pl = sl[h * 32 + ql];
        float mN = fmaxf(m_run, pm);
        float w0_ = exp2f(m_run - mN), w1_ = exp2f(pm - mN);
        float inv = 1.0f / (l_tot * w0_ + pl * w1_);
#pragma unroll
        for (int T = 0; T < 2; T++)
#pragma unroll
            for (int j = 0; j < 8; j++) {
                int dw = T * 16 + (j & 1) + 4 * (j >> 1) + 2 * hi;
                int ad = soff(ql, h * 32 + dw);
                unsigned pv = sO[ad];
                float a = (T == 0) ? o0[2 * j] : o1[2 * j];
                float b = (T == 0) ? o0[2 * j + 1] : o1[2 * j + 1];
                float r0 = (a * w0_ + bf2f((u16)(pv & 0xffff)) * w1_) * inv;
                float r1 = (b * w0_ + bf2f((u16)(pv >> 16)) * w1_) * inv;
                sO[ad] = pk2(r0, r1);
            }
    }
    __syncthreads();

    // ---- phase 3: LayerNorm, wave wid -> rows 2*wid, 2*wid+1
#pragma unroll
    for (int rr = 0; rr < 2; rr++) {
        int r = wid * 2 + rr;
        uint4 pw = *(const uint4*)(&sO[r * 256 + ((lane ^ (r & 7)) << 2)]);
        float v[8];
        v[0] = bf2f((u16)(pw.x & 0xffff)); v[1] = bf2f((u16)(pw.x >> 16));
        v[2] = bf2f((u16)(pw.y & 0xffff)); v[3] = bf2f((u16)(pw.y >> 16));
        v[4] = bf2f((u16)(pw.z & 0xffff)); v[5] = bf2f((u16)(pw.z >> 16));
        v[6] = bf2f((u16)(pw.w & 0xffff)); v[7] = bf2f((u16)(pw.w >> 16));
        float sum = 0.f, sq = 0.f;
#pragma unroll
        for (int j = 0; j < 8; j++) { sum += v[j]; sq += v[j] * v[j]; }
#pragma unroll
        for (int msk = 1; msk <= 32; msk <<= 1) { sum += __shfl_xor(sum, msk); sq += __shfl_xor(sq, msk); }
        float mu = sum * (1.f / DMODEL);
        float var = sq * (1.f / DMODEL) - mu * mu;
        float rstd = rsqrtf(var + 1e-5f);
        float4 g0 = *(const float4*)(ln_g + lane * 8);
        float4 g1 = *(const float4*)(ln_g + lane * 8 + 4);
        float4 b0 = *(const float4*)(ln_b + lane * 8);
        float4 b1 = *(const float4*)(ln_b + lane * 8 + 4);
        float o[8];
        o[0] = (v[0] - mu) * rstd * g0.x + b0.x; o[1] = (v[1] - mu) * rstd * g0.y + b0.y;
        o[2] = (v[2] - mu) * rstd * g0.z + b0.z; o[3] = (v[3] - mu) * rstd * g0.w + b0.w;
        o[4] = (v[4] - mu) * rstd * g1.x + b1.x; o[5] = (v[5] - mu) * rstd * g1.y + b1.y;
        o[6] = (v[6] - mu) * rstd * g1.z + b1.z; o[7] = (v[7] - mu) * rstd * g1.w + b1.w;
        float* op = Out + (size_t)(q0 + r) * DMODEL + lane * 8;
        *(float4*)op = *(float4*)&o[0];
        *(float4*)(op + 4) = *(float4*)&o[4];
    }
}

extern "C" void kernel_launch(void* const* d_in, const int* in_sizes, int n_in,
                              void* d_out, int out_size, void* d_ws, size_t ws_size,
                              hipStream_t stream)
{
    const float* x      = (const float*)d_in[0];
    const float* W_proj = (const float*)d_in[1];
    const float* b_proj = (const float*)d_in[2];
    const float* W_q    = (const float*)d_in[3];
    const float* b_q    = (const float*)d_in[4];
    const float* W_k    = (const float*)d_in[5];
    const float* b_k    = (const float*)d_in[6];
    const float* W_v    = (const float*)d_in[7];
    const float* b_v    = (const float*)d_in[8];
    const float* k_buf  = (const float*)d_in[9];
    const float* v_buf  = (const float*)d_in[10];
    const float* ln_g   = (const float*)d_in[11];
    const float* ln_b   = (const float*)d_in[12];
    const int*   c_idx  = (const int*)d_in[13];
    float* out = (float*)d_out;

    char* ws = (char*)d_ws;
    size_t off = 0;
    auto alloc = [&](size_t bytes) -> void* {
        void* p = ws + off;
        off += (bytes + 255) & ~(size_t)255;
        return p;
    };
    u16* x_bf   = (u16*)alloc((size_t)NQ * DMODEL * 2);
    u16* kb_bf  = (u16*)alloc((size_t)NC * DMODEL * 2);
    u16* vb_bf  = (u16*)alloc((size_t)NC * DMODEL * 2);
    u16* Wp_bf  = (u16*)alloc((size_t)DMODEL * DMODEL * 2);
    u16* Wq_t   = (u16*)alloc((size_t)DMODEL * DMODEL * 2);
    u16* Wk_t   = (u16*)alloc((size_t)DMODEL * DMODEL * 2);
    u16* Wv_t   = (u16*)alloc((size_t)DMODEL * DMODEL * 2);
    u16* WcombT = (u16*)alloc((size_t)DMODEL * DMODEL * 2);
    u16* Qm     = (u16*)alloc((size_t)NQ * DMODEL * 2);
    u16* Km     = (u16*)alloc((size_t)NC * DMODEL * 2);
    u16* Vtm    = (u16*)alloc((size_t)DMODEL * NC * 2);
    int*   counts = (int*)alloc(NC * 4);
    float* bcomb  = (float*)alloc(DMODEL * 4);

    hipMemsetAsync(counts, 0, NC * 4, stream);

    k_prep<<<dim3(7298), dim3(256), 0, stream>>>(
        x, k_buf, v_buf, W_proj, W_q, W_k, W_v, b_proj, b_q, c_idx,
        x_bf, kb_bf, vb_bf, Wp_bf, Wq_t, Wk_t, Wv_t, counts, bcomb);

    // WcombT = Wq^T @ Wp^T  (so Q = x @ (Wp Wq) uses Bt=WcombT)
    k_gemm_bt<0><<<dim3(4, 4), dim3(256), 0, stream>>>(Wq_t, Wp_bf, nullptr, WcombT, DMODEL, DMODEL, DMODEL);
    k_gemm_bt<0><<<dim3(4, 16), dim3(256), 0, stream>>>(kb_bf, Wk_t, b_k, Km, NC, DMODEL, DMODEL);
    k_gemm_bt<1><<<dim3(4, 16), dim3(256), 0, stream>>>(vb_bf, Wv_t, b_v, Vtm, NC, DMODEL, DMODEL);
    k_gemm_bt<0><<<dim3(4, 64), dim3(256), 0, stream>>>(x_bf, WcombT, bcomb, Qm, NQ, DMODEL, DMODEL);

    // scale2 = (1/sqrt(512)) * log2(e); bias in log2 domain (computed in-kernel)
    k_attn3<<<dim3(NQ / 32), dim3(1024), 0, stream>>>(Qm, Km, Vtm, counts, ln_g, ln_b, out, 0.06375872f);
    (void)in_sizes; (void)n_in; (void)out_size; (void)ws_size;
}

// Round 5
// 218.578 us; speedup vs baseline: 1.2681x; 1.0941x over previous
//
#include <hip/hip_runtime.h>
#include <math.h>

typedef __bf16 bf16x8 __attribute__((ext_vector_type(8)));
typedef __bf16 bf16x2 __attribute__((ext_vector_type(2)));
typedef float f32x4 __attribute__((ext_vector_type(4)));
typedef float f32x16 __attribute__((ext_vector_type(16)));
typedef unsigned short u16;

#define NQ 8192
#define DMODEL 512
#define NHEAD 8
#define DH 64
#define NC 2048
#define NIDX 100000

__device__ __forceinline__ u16 f2bf(float f) {
    unsigned u = __float_as_uint(f);
    u += 0x7fffu + ((u >> 16) & 1u);
    return (u16)(u >> 16);
}
__device__ __forceinline__ float bf2f(u16 h) {
    return __uint_as_float(((unsigned)h) << 16);
}
__device__ __forceinline__ unsigned pk2(float a, float b) {
    bf16x2 t; t[0] = (__bf16)a; t[1] = (__bf16)b;   // v_cvt_pk_bf16_f32
    return __builtin_bit_cast(unsigned, t);
}
// swizzled u32 index into sO[32][256]: 16B-block XOR by row
__device__ __forceinline__ int soff(int q, int col) {
    return q * 256 + ((((col >> 2) ^ (q & 7)) << 2) | (col & 3));
}

// ---------------- fused preamble: converts + transposes + hist + bcomb ----------------
__global__ __launch_bounds__(256) void k_prep(
    const float* __restrict__ x, const float* __restrict__ kb, const float* __restrict__ vb,
    const float* __restrict__ Wp, const float* __restrict__ Wq, const float* __restrict__ Wk,
    const float* __restrict__ Wv, const float* __restrict__ bp, const float* __restrict__ bq_,
    const int* __restrict__ cidx,
    u16* __restrict__ x_bf, u16* __restrict__ kb_bf, u16* __restrict__ vb_bf,
    u16* __restrict__ Wp_bf, u16* __restrict__ Wq_t, u16* __restrict__ Wk_t,
    u16* __restrict__ Wv_t, int* __restrict__ counts, float* __restrict__ bcomb)
{
    __shared__ float tile[32][33];
    int bid = blockIdx.x, tid = threadIdx.x;
    if (bid < 6400) {
        const float* src; u16* dst; int i;
        if (bid < 4096)      { src = x;  dst = x_bf;  i = bid; }
        else if (bid < 5120) { src = kb; dst = kb_bf; i = bid - 4096; }
        else if (bid < 6144) { src = vb; dst = vb_bf; i = bid - 5120; }
        else                 { src = Wp; dst = Wp_bf; i = bid - 6144; }
        int e = (i * 256 + tid) * 4;
        float4 v = *(const float4*)(src + e);
        ushort4 o;
        o.x = f2bf(v.x); o.y = f2bf(v.y); o.z = f2bf(v.z); o.w = f2bf(v.w);
        *(ushort4*)(dst + e) = o;
    } else if (bid < 7168) {
        const float* W; u16* Wt; int tb;
        if (bid < 6656)      { W = Wq; Wt = Wq_t; tb = bid - 6400; }
        else if (bid < 6912) { W = Wk; Wt = Wk_t; tb = bid - 6656; }
        else                 { W = Wv; Wt = Wv_t; tb = bid - 6912; }
        int c0 = (tb & 15) * 32, r0 = (tb >> 4) * 32;
        int tx = tid & 31, ty = tid >> 5;
#pragma unroll
        for (int i = 0; i < 4; i++)
            tile[ty + i * 8][tx] = W[(size_t)(r0 + ty + i * 8) * DMODEL + c0 + tx];
        __syncthreads();
#pragma unroll
        for (int i = 0; i < 4; i++)
            Wt[(size_t)(c0 + ty + i * 8) * DMODEL + r0 + tx] = f2bf(tile[tx][ty + i * 8]);
    } else if (bid < 7296) {
        for (int i = (bid - 7168) * 256 + tid; i < NIDX; i += 128 * 256)
            atomicAdd(&counts[cidx[i]], 1);
    } else {
        int j = (bid - 7296) * 256 + tid;
        float s = bq_[j];
        for (int k = 0; k < DMODEL; k++) s += bp[k] * Wq[(size_t)k * DMODEL + j];
        bcomb[j] = s;
    }
}

// ---------------- bf16 GEMM: C = A[M][K] * Bt[N][K]^T + bias[N] ----------------
template <int OUT_T>
__global__ __launch_bounds__(256) void k_gemm_bt(
    const u16* __restrict__ A, const u16* __restrict__ Bt,
    const float* __restrict__ bias, u16* __restrict__ Cmat,
    int M, int N, int K)
{
    constexpr int LDP = 40;
    __shared__ __align__(16) u16 As[128 * LDP];
    __shared__ __align__(16) u16 Bs[128 * LDP];
    int tid = threadIdx.x;
    int lane = tid & 63, wid = tid >> 6;
    int wrow = (wid >> 1) * 64, wcol = (wid & 1) * 64;
    int m0 = blockIdx.y * 128, n0 = blockIdx.x * 128;
    int lr = lane & 15, lg = lane >> 4;
    f32x4 acc[4][4] = {};

    for (int k0 = 0; k0 < K; k0 += 32) {
#pragma unroll
        for (int c = 0; c < 2; c++) {
            int ch = tid + c * 256;
            int row = ch >> 2, colc = (ch & 3) * 8;
            uint4 av = *(const uint4*)(A + (size_t)(m0 + row) * K + k0 + colc);
            *(uint4*)(&As[row * LDP + colc]) = av;
            uint4 bv = *(const uint4*)(Bt + (size_t)(n0 + row) * K + k0 + colc);
            *(uint4*)(&Bs[row * LDP + colc]) = bv;
        }
        __syncthreads();
        bf16x8 af[4], bfr[4];
#pragma unroll
        for (int m = 0; m < 4; m++)
            af[m] = *(const bf16x8*)(&As[(wrow + m * 16 + lr) * LDP + lg * 8]);
#pragma unroll
        for (int n = 0; n < 4; n++)
            bfr[n] = *(const bf16x8*)(&Bs[(wcol + n * 16 + lr) * LDP + lg * 8]);
#pragma unroll
        for (int m = 0; m < 4; m++)
#pragma unroll
            for (int n = 0; n < 4; n++)
                acc[m][n] = __builtin_amdgcn_mfma_f32_16x16x32_bf16(af[m], bfr[n], acc[m][n], 0, 0, 0);
        __syncthreads();
    }
#pragma unroll
    for (int n = 0; n < 4; n++) {
        int col = n0 + wcol + n * 16 + lr;
        float bv = bias ? bias[col] : 0.0f;
#pragma unroll
        for (int m = 0; m < 4; m++) {
            int rbase = m0 + wrow + m * 16 + lg * 4;
            if (OUT_T) {
                ushort4 o4;
                o4.x = f2bf(acc[m][n][0] + bv);
                o4.y = f2bf(acc[m][n][1] + bv);
                o4.z = f2bf(acc[m][n][2] + bv);
                o4.w = f2bf(acc[m][n][3] + bv);
                *(ushort4*)(Cmat + (size_t)col * M + rbase) = o4;
            } else {
#pragma unroll
                for (int r = 0; r < 4; r++)
                    Cmat[(size_t)(rbase + r) * N + col] = f2bf(acc[m][n][r] + bv);
            }
        }
    }
}

// ---------------- fused attention + LayerNorm ----------------
// grid(NQ/32); block 512 = 8 waves = 8 heads. Wave: 32 q-rows, one head, ALL 2048
// centroids. Swapped QK^T (mfma(K,Q)) -> lane-local softmax, in-register P repack
// (pk2 + shfl_xor(32)) -> PV as O^T. K and V both prefetched one chunk ahead.
// __launch_bounds__(512,2): 256 unified regs/wave -> zero spill by construction.
__global__ __launch_bounds__(512, 2) void k_attn4(
    const u16* __restrict__ Q, const u16* __restrict__ Km, const u16* __restrict__ Vt,
    const int* __restrict__ counts, const float* __restrict__ ln_g,
    const float* __restrict__ ln_b, float* __restrict__ Out, float scale2)
{
    __shared__ float sbias[NC];          // 8 KB, log2(count)
    __shared__ unsigned sO[32 * 256];    // 32 KB, swizzled packed O

    int tid = threadIdx.x;
    int lane = tid & 63, wid = tid >> 6;
    int h = wid;
    int ql = lane & 31, hi = lane >> 5;
    int q0 = blockIdx.x * 32;
    int hbase = h * DH;

#pragma unroll
    for (int i = 0; i < 4; i++)
        sbias[tid + i * 512] = log2f((float)counts[tid + i * 512]);

    bf16x8 qf[4];
#pragma unroll
    for (int m = 0; m < 4; m++)
        qf[m] = *(const bf16x8*)(Q + (size_t)(q0 + ql) * DMODEL + hbase + m * 16 + hi * 8);

    // preload chunk 0 K and V fragments
    bf16x8 kf[4], vf[4];
#pragma unroll
    for (int m = 0; m < 4; m++)
        kf[m] = *(const bf16x8*)(Km + (size_t)ql * DMODEL + hbase + m * 16 + hi * 8);
#pragma unroll
    for (int T = 0; T < 2; T++)
#pragma unroll
        for (int ss = 0; ss < 2; ss++)
            vf[T * 2 + ss] = *(const bf16x8*)(Vt + (size_t)(hbase + T * 32 + ql) * NC + ss * 16 + hi * 8);

    f32x16 o0 = {}, o1 = {};
    float m_run = -1e30f, l_part = 0.f;

    __syncthreads();   // sbias ready

    for (int t = 0; t < NC / 32; t++) {
        int c0 = t * 32;
        int cn = ((t + 1) & (NC / 32 - 1)) * 32;

        f32x4 bq[4];
#pragma unroll
        for (int j = 0; j < 4; j++)
            bq[j] = *(const f32x4*)(sbias + c0 + 8 * j + 4 * hi);

        // QK^T (swapped): acc[c][q]
        f32x16 acc = {};
        __builtin_amdgcn_s_setprio(1);
#pragma unroll
        for (int m = 0; m < 4; m++)
            acc = __builtin_amdgcn_mfma_f32_32x32x16_bf16(kf[m], qf[m], acc, 0, 0, 0);
        __builtin_amdgcn_s_setprio(0);

        // prefetch next K into just-freed regs (consumed next iteration)
#pragma unroll
        for (int m = 0; m < 4; m++)
            kf[m] = *(const bf16x8*)(Km + (size_t)(cn + ql) * DMODEL + hbase + m * 16 + hi * 8);

        float s[16];
#pragma unroll
        for (int r = 0; r < 16; r++)
            s[r] = acc[r] * scale2 + bq[r >> 2][r & 3];

        float mx = s[0];
#pragma unroll
        for (int r = 1; r < 16; r++) mx = fmaxf(mx, s[r]);
        mx = fmaxf(mx, __shfl_xor(mx, 32));

        if (__any(mx > m_run + 11.f)) {            // defer-max (log2 domain)
            float mn = fmaxf(m_run, mx);
            float corr = exp2f(m_run - mn);
            m_run = mn; l_part *= corr;
#pragma unroll
            for (int r = 0; r < 16; r++) { o0[r] *= corr; o1[r] *= corr; }
        }

        float rs = 0.f;
#pragma unroll
        for (int r = 0; r < 16; r++) {
            s[r] = exp2f(s[r] - m_run);
            rs += s[r];
        }
        l_part += rs;

        // pack P pairs, exchange with partner lane (lane^32), assemble B-frags
        unsigned u[8], pu[8];
#pragma unroll
        for (int j = 0; j < 8; j++) u[j] = pk2(s[2 * j], s[2 * j + 1]);
#pragma unroll
        for (int j = 0; j < 8; j++) pu[j] = (unsigned)__shfl_xor((int)u[j], 32);

        uint4 w0, w1;
        w0.x = hi ? pu[2] : u[0];  w0.y = hi ? pu[3] : u[1];
        w0.z = hi ? u[2] : pu[0];  w0.w = hi ? u[3] : pu[1];
        w1.x = hi ? pu[6] : u[4];  w1.y = hi ? pu[7] : u[5];
        w1.z = hi ? u[6] : pu[4];  w1.w = hi ? u[7] : pu[5];
        bf16x8 pb0 = __builtin_bit_cast(bf16x8, w0);
        bf16x8 pb1 = __builtin_bit_cast(bf16x8, w1);

        // PV: O^T[d][q] += V^T-frag x P-frag
        __builtin_amdgcn_s_setprio(1);
        o0 = __builtin_amdgcn_mfma_f32_32x32x16_bf16(vf[0], pb0, o0, 0, 0, 0);
        o0 = __builtin_amdgcn_mfma_f32_32x32x16_bf16(vf[1], pb1, o0, 0, 0, 0);
        o1 = __builtin_amdgcn_mfma_f32_32x32x16_bf16(vf[2], pb0, o1, 0, 0, 0);
        o1 = __builtin_amdgcn_mfma_f32_32x32x16_bf16(vf[3], pb1, o1, 0, 0, 0);
        __builtin_amdgcn_s_setprio(0);

        // prefetch next V (consumed next iteration; latency hidden by next QK+softmax)
#pragma unroll
        for (int T = 0; T < 2; T++)
#pragma unroll
            for (int ss = 0; ss < 2; ss++)
                vf[T * 2 + ss] = *(const bf16x8*)(Vt + (size_t)(hbase + T * 32 + ql) * NC + cn + ss * 16 + hi * 8);
    }

    float l_tot = l_part + __shfl_xor(l_part, 32);
    float inv = 1.0f / l_tot;

    // ---- normalized packed O -> LDS (swizzled)
#pragma unroll
    for (int T = 0; T < 2; T++)
#pragma unroll
        for (int j = 0; j < 8; j++) {
            int dw = T * 16 + (j & 1) + 4 * (j >> 1) + 2 * hi;
            float a = (T == 0) ? o0[2 * j] : o1[2 * j];
            float b = (T == 0) ? o0[2 * j + 1] : o1[2 * j + 1];
            sO[soff(ql, h * 32 + dw)] = pk2(a * inv, b * inv);
        }
    __syncthreads();

    // ---- LayerNorm: wave wid -> rows 4*wid .. 4*wid+3
    float4 g0 = *(const float4*)(ln_g + lane * 8);
    float4 g1 = *(const float4*)(ln_g + lane * 8 + 4);
    float4 b0 = *(const float4*)(ln_b + lane * 8);
    float4 b1 = *(const float4*)(ln_b + lane * 8 + 4);
#pragma unroll
    for (int rr = 0; rr < 4; rr++) {
        int r = wid * 4 + rr;
        uint4 pw = *(const uint4*)(&sO[r * 256 + ((lane ^ (r & 7)) << 2)]);
        float v[8];
        v[0] = bf2f((u16)(pw.x & 0xffff)); v[1] = bf2f((u16)(pw.x >> 16));
        v[2] = bf2f((u16)(pw.y & 0xffff)); v[3] = bf2f((u16)(pw.y >> 16));
        v[4] = bf2f((u16)(pw.z & 0xffff)); v[5] = bf2f((u16)(pw.z >> 16));
        v[6] = bf2f((u16)(pw.w & 0xffff)); v[7] = bf2f((u16)(pw.w >> 16));
        float sum = 0.f, sq = 0.f;
#pragma unroll
        for (int j = 0; j < 8; j++) { sum += v[j]; sq += v[j] * v[j]; }
#pragma unroll
        for (int msk = 1; msk <= 32; msk <<= 1) { sum += __shfl_xor(sum, msk); sq += __shfl_xor(sq, msk); }
        float mu = sum * (1.f / DMODEL);
        float var = sq * (1.f / DMODEL) - mu * mu;
        float rstd = rsqrtf(var + 1e-5f);
        float o[8];
        o[0] = (v[0] - mu) * rstd * g0.x + b0.x; o[1] = (v[1] - mu) * rstd * g0.y + b0.y;
        o[2] = (v[2] - mu) * rstd * g0.z + b0.z; o[3] = (v[3] - mu) * rstd * g0.w + b0.w;
        o[4] = (v[4] - mu) * rstd * g1.x + b1.x; o[5] = (v[5] - mu) * rstd * g1.y + b1.y;
        o[6] = (v[6] - mu) * rstd * g1.z + b1.z; o[7] = (v[7] - mu) * rstd * g1.w + b1.w;
        float* op = Out + (size_t)(q0 + r) * DMODEL + lane * 8;
        *(float4*)op = *(float4*)&o[0];
        *(float4*)(op + 4) = *(float4*)&o[4];
    }
}

extern "C" void kernel_launch(void* const* d_in, const int* in_sizes, int n_in,
                              void* d_out, int out_size, void* d_ws, size_t ws_size,
                              hipStream_t stream)
{
    const float* x      = (const float*)d_in[0];
    const float* W_proj = (const float*)d_in[1];
    const float* b_proj = (const float*)d_in[2];
    const float* W_q    = (const float*)d_in[3];
    const float* b_q    = (const float*)d_in[4];
    const float* W_k    = (const float*)d_in[5];
    const float* b_k    = (const float*)d_in[6];
    const float* W_v    = (const float*)d_in[7];
    const float* b_v    = (const float*)d_in[8];
    const float* k_buf  = (const float*)d_in[9];
    const float* v_buf  = (const float*)d_in[10];
    const float* ln_g   = (const float*)d_in[11];
    const float* ln_b   = (const float*)d_in[12];
    const int*   c_idx  = (const int*)d_in[13];
    float* out = (float*)d_out;

    char* ws = (char*)d_ws;
    size_t off = 0;
    auto alloc = [&](size_t bytes) -> void* {
        void* p = ws + off;
        off += (bytes + 255) & ~(size_t)255;
        return p;
    };
    u16* x_bf   = (u16*)alloc((size_t)NQ * DMODEL * 2);
    u16* kb_bf  = (u16*)alloc((size_t)NC * DMODEL * 2);
    u16* vb_bf  = (u16*)alloc((size_t)NC * DMODEL * 2);
    u16* Wp_bf  = (u16*)alloc((size_t)DMODEL * DMODEL * 2);
    u16* Wq_t   = (u16*)alloc((size_t)DMODEL * DMODEL * 2);
    u16* Wk_t   = (u16*)alloc((size_t)DMODEL * DMODEL * 2);
    u16* Wv_t   = (u16*)alloc((size_t)DMODEL * DMODEL * 2);
    u16* WcombT = (u16*)alloc((size_t)DMODEL * DMODEL * 2);
    u16* Qm     = (u16*)alloc((size_t)NQ * DMODEL * 2);
    u16* Km     = (u16*)alloc((size_t)NC * DMODEL * 2);
    u16* Vtm    = (u16*)alloc((size_t)DMODEL * NC * 2);
    int*   counts = (int*)alloc(NC * 4);
    float* bcomb  = (float*)alloc(DMODEL * 4);

    hipMemsetAsync(counts, 0, NC * 4, stream);

    k_prep<<<dim3(7298), dim3(256), 0, stream>>>(
        x, k_buf, v_buf, W_proj, W_q, W_k, W_v, b_proj, b_q, c_idx,
        x_bf, kb_bf, vb_bf, Wp_bf, Wq_t, Wk_t, Wv_t, counts, bcomb);

    // WcombT = Wq^T @ Wp^T  (so Q = x @ (Wp Wq) uses Bt=WcombT)
    k_gemm_bt<0><<<dim3(4, 4), dim3(256), 0, stream>>>(Wq_t, Wp_bf, nullptr, WcombT, DMODEL, DMODEL, DMODEL);
    k_gemm_bt<0><<<dim3(4, 16), dim3(256), 0, stream>>>(kb_bf, Wk_t, b_k, Km, NC, DMODEL, DMODEL);
    k_gemm_bt<1><<<dim3(4, 16), dim3(256), 0, stream>>>(vb_bf, Wv_t, b_v, Vtm, NC, DMODEL, DMODEL);
    k_gemm_bt<0><<<dim3(4, 64), dim3(256), 0, stream>>>(x_bf, WcombT, bcomb, Qm, NQ, DMODEL, DMODEL);

    // scale2 = (1/sqrt(512)) * log2(e); bias in log2 domain (computed in-kernel)
    k_attn4<<<dim3(NQ / 32), dim3(512), 0, stream>>>(Qm, Km, Vtm, counts, ln_g, ln_b, out, 0.06375872f);
    (void)in_sizes; (void)n_in; (void)out_size; (void)ws_size;
}